// Round 1
// baseline (547.032 us; speedup 1.0000x reference)
//
#include <hip/hip_runtime.h>
#include <math.h>

#define BS_TOK 16384   // B*S
#define DIM    2048    // D
#define NEXP   64      // E
#define DHID   1024    // D/2

typedef __attribute__((ext_vector_type(8))) _Float16 f16x8;
typedef __attribute__((ext_vector_type(4))) float    f32x4;

__device__ __forceinline__ float gelu_f(float x) {
  return 0.5f * x * (1.0f + erff(x * 0.70710678118654752440f));
}

// ---------------- LayerNorm -> f16 H ----------------
__global__ __launch_bounds__(256) void ln_kernel(const float* __restrict__ X,
                                                 const float* __restrict__ gamma,
                                                 const float* __restrict__ beta,
                                                 _Float16* __restrict__ H) {
  const int t   = blockIdx.x;
  const int tid = threadIdx.x;
  const float* xr = X + (size_t)t * DIM;
  const float4 a = *(const float4*)(xr + tid * 8);
  const float4 b = *(const float4*)(xr + tid * 8 + 4);
  float xv[8] = {a.x, a.y, a.z, a.w, b.x, b.y, b.z, b.w};
  float s = 0.f, q = 0.f;
#pragma unroll
  for (int j = 0; j < 8; ++j) { s += xv[j]; q += xv[j] * xv[j]; }
#pragma unroll
  for (int off = 32; off > 0; off >>= 1) {
    s += __shfl_xor(s, off);
    q += __shfl_xor(q, off);
  }
  __shared__ float red[8];
  const int w = tid >> 6;
  if ((tid & 63) == 0) { red[w * 2] = s; red[w * 2 + 1] = q; }
  __syncthreads();
  const float ts = red[0] + red[2] + red[4] + red[6];
  const float tq = red[1] + red[3] + red[5] + red[7];
  const float mu  = ts * (1.0f / DIM);
  const float var = tq * (1.0f / DIM) - mu * mu;
  const float rs  = rsqrtf(var + 1e-5f);
  f16x8 h;
#pragma unroll
  for (int j = 0; j < 8; ++j) {
    const int c = tid * 8 + j;
    h[j] = (_Float16)((xv[j] - mu) * rs * gamma[c] + beta[c]);
  }
  *(f16x8*)(H + (size_t)t * DIM + tid * 8) = h;
}

// ---------------- W1 fp32 -> f16 ----------------
__global__ __launch_bounds__(256) void w1cast_kernel(const float* __restrict__ W1,
                                                     _Float16* __restrict__ W1h) {
  const int i = (blockIdx.x * 256 + threadIdx.x) * 8;
  const float4 a = *(const float4*)(W1 + i);
  const float4 b = *(const float4*)(W1 + i + 4);
  f16x8 o;
  o[0] = (_Float16)a.x; o[1] = (_Float16)a.y; o[2] = (_Float16)a.z; o[3] = (_Float16)a.w;
  o[4] = (_Float16)b.x; o[5] = (_Float16)b.y; o[6] = (_Float16)b.z; o[7] = (_Float16)b.w;
  *(f16x8*)(W1h + i) = o;
}

// ---------------- gate: logits = X . Wg^T  (fp32, 64x64 tile) ----------------
__global__ __launch_bounds__(256) void gate_kernel(const float* __restrict__ X,
                                                   const float* __restrict__ Wg,
                                                   float* __restrict__ logits) {
  __shared__ float sA[16 * 68];  // [k][m], padded
  __shared__ float sB[16 * 68];  // [k][e], padded
  const int tid = threadIdx.x;
  const int m0  = blockIdx.x * 64;
  const int ty  = tid >> 4, tx = tid & 15;
  const int lrow = tid >> 2, lkq = tid & 3;
  float accA[4][4] = {};
  float accB[4][4] = {};
  for (int kt = 0; kt < DIM; kt += 16) {
    const float4 av = *(const float4*)(X  + (size_t)(m0 + lrow) * DIM + kt + lkq * 4);
    const float4 bv = *(const float4*)(Wg + (size_t)lrow        * DIM + kt + lkq * 4);
    __syncthreads();
    sA[(lkq*4+0)*68 + lrow] = av.x; sA[(lkq*4+1)*68 + lrow] = av.y;
    sA[(lkq*4+2)*68 + lrow] = av.z; sA[(lkq*4+3)*68 + lrow] = av.w;
    sB[(lkq*4+0)*68 + lrow] = bv.x; sB[(lkq*4+1)*68 + lrow] = bv.y;
    sB[(lkq*4+2)*68 + lrow] = bv.z; sB[(lkq*4+3)*68 + lrow] = bv.w;
    __syncthreads();
#pragma unroll
    for (int k = 0; k < 16; ++k) {
      const float4 a4 = *(const float4*)(sA + k * 68 + ty * 4);
      const float4 b4 = *(const float4*)(sB + k * 68 + tx * 4);
      const float ar[4] = {a4.x, a4.y, a4.z, a4.w};
      const float br[4] = {b4.x, b4.y, b4.z, b4.w};
      if (k & 1) {
#pragma unroll
        for (int i = 0; i < 4; ++i)
#pragma unroll
          for (int j = 0; j < 4; ++j) accB[i][j] += ar[i] * br[j];
      } else {
#pragma unroll
        for (int i = 0; i < 4; ++i)
#pragma unroll
          for (int j = 0; j < 4; ++j) accA[i][j] += ar[i] * br[j];
      }
    }
  }
#pragma unroll
  for (int i = 0; i < 4; ++i) {
    float4 o;
    o.x = accA[i][0] + accB[i][0];
    o.y = accA[i][1] + accB[i][1];
    o.z = accA[i][2] + accB[i][2];
    o.w = accA[i][3] + accB[i][3];
    *(float4*)(logits + (size_t)(m0 + ty * 4 + i) * NEXP + tx * 4) = o;
  }
}

// ------- predictor GEMM: H1 = gelu(H . W1^T); z[t] += sum_n H1*W2 (fused) -------
__global__ __launch_bounds__(256) void g2_kernel(const _Float16* __restrict__ H,
                                                 const _Float16* __restrict__ W1h,
                                                 const float* __restrict__ W2,
                                                 float* __restrict__ diffz) {
  __shared__ __align__(16) _Float16 sA[128 * 32];
  __shared__ __align__(16) _Float16 sB[128 * 32];
  const int tid  = threadIdx.x;
  const int n0   = blockIdx.x * 128;   // n fast -> W1 tiles stay L2-hot
  const int m0   = blockIdx.y * 128;
  const int w    = tid >> 6, lane = tid & 63;
  const int wr   = w >> 1,  wc   = w & 1;
  const int col  = lane & 15, quad = lane >> 4;
  const int row0 = tid >> 2,  kp = tid & 3;
  const int row1 = row0 + 64;
  f32x4 acc[4][4] = {};
  for (int kt = 0; kt < DIM; kt += 32) {
    const f16x8 va0 = *(const f16x8*)(H   + (size_t)(m0 + row0) * DIM + kt + kp * 8);
    const f16x8 va1 = *(const f16x8*)(H   + (size_t)(m0 + row1) * DIM + kt + kp * 8);
    const f16x8 vb0 = *(const f16x8*)(W1h + (size_t)(n0 + row0) * DIM + kt + kp * 8);
    const f16x8 vb1 = *(const f16x8*)(W1h + (size_t)(n0 + row1) * DIM + kt + kp * 8);
    __syncthreads();
    *(f16x8*)(sA + tid * 8)         = va0;
    *(f16x8*)(sA + (256 + tid) * 8) = va1;
    *(f16x8*)(sB + tid * 8)         = vb0;
    *(f16x8*)(sB + (256 + tid) * 8) = vb1;
    __syncthreads();
    f16x8 af[4], bf[4];
#pragma unroll
    for (int mi = 0; mi < 4; ++mi)
      af[mi] = *(const f16x8*)(sA + (wr * 64 + mi * 16 + col) * 32 + quad * 8);
#pragma unroll
    for (int ni = 0; ni < 4; ++ni)
      bf[ni] = *(const f16x8*)(sB + (wc * 64 + ni * 16 + col) * 32 + quad * 8);
#pragma unroll
    for (int mi = 0; mi < 4; ++mi)
#pragma unroll
      for (int ni = 0; ni < 4; ++ni)
        acc[mi][ni] = __builtin_amdgcn_mfma_f32_16x16x32_f16(af[mi], bf[ni], acc[mi][ni], 0, 0, 0);
  }
  // epilogue: gelu -> * W2 -> reduce over the 128 n-cols this block owns
  float w2v[4];
#pragma unroll
  for (int ni = 0; ni < 4; ++ni) w2v[ni] = W2[n0 + wc * 64 + ni * 16 + col];
#pragma unroll
  for (int mi = 0; mi < 4; ++mi) {
#pragma unroll
    for (int reg = 0; reg < 4; ++reg) {
      float v = 0.f;
#pragma unroll
      for (int ni = 0; ni < 4; ++ni) v += gelu_f(acc[mi][ni][reg]) * w2v[ni];
      v += __shfl_xor(v, 1);
      v += __shfl_xor(v, 2);
      v += __shfl_xor(v, 4);
      v += __shfl_xor(v, 8);
      if (col == 0)
        atomicAdd(diffz + m0 + wr * 64 + mi * 16 + quad * 4 + reg, v);
    }
  }
}

// ---------------- per-token finalize: one wave per token ----------------
__global__ __launch_bounds__(256) void finalize_kernel(const float* __restrict__ logits,
                                                       const float* __restrict__ diffz,
                                                       float* __restrict__ out_idx,
                                                       float* __restrict__ out_scores,
                                                       float* __restrict__ out_probs,
                                                       float* __restrict__ imp_acc,
                                                       float* __restrict__ load_acc) {
  const int tid  = threadIdx.x;
  const int w    = tid >> 6, lane = tid & 63;
  const int t    = blockIdx.x * 4 + w;
  const float L  = logits[(size_t)t * NEXP + lane];
  const float z  = diffz[t];
  const float d  = 1.0f / (1.0f + expf(-z));
  const float l  = L / (1.0f + d);          // TEMP == 1
  // softmax
  float m = l;
#pragma unroll
  for (int off = 32; off > 0; off >>= 1) m = fmaxf(m, __shfl_xor(m, off));
  float p = expf(l - m);
  float s = p;
#pragma unroll
  for (int off = 32; off > 0; off >>= 1) s += __shfl_xor(s, off);
  p /= s;
  // top-1 (jax tie-break: lower index wins)
  float v = l; int bi = lane;
#pragma unroll
  for (int off = 32; off > 0; off >>= 1) {
    const float ov = __shfl_xor(v, off);
    const int   oi = __shfl_xor(bi, off);
    if (ov > v || (ov == v && oi < bi)) { v = ov; bi = oi; }
  }
  const int i1 = bi;
  // top-2
  float v2 = (lane == i1) ? -INFINITY : l;
  int bi2 = lane;
#pragma unroll
  for (int off = 32; off > 0; off >>= 1) {
    const float ov = __shfl_xor(v2, off);
    const int   oi = __shfl_xor(bi2, off);
    if (ov > v2 || (ov == v2 && oi < bi2)) { v2 = ov; bi2 = oi; }
  }
  const int i2 = bi2;
  const float p1 = __shfl(p, i1);
  const float p2 = __shfl(p, i2);
  const float s1 = (1.0f - p1) + p1;        // straight-through, fp32-faithful
  const float s2 = (1.0f - p2) + p2;
  const float den = fmaxf(s1 + s2, 1e-9f);
  if (lane == 0) {
    out_idx[t * 2]       = (float)i1;
    out_idx[t * 2 + 1]   = (float)i2;
    out_scores[t * 2]     = s1 / den;
    out_scores[t * 2 + 1] = s2 / den;
  }
  out_probs[(size_t)t * NEXP + lane] = p;
  __shared__ float s_imp[256];
  __shared__ float s_hard[256];
  s_imp[tid]  = p;
  s_hard[tid] = (lane == i1 || lane == i2) ? 1.0f : 0.0f;
  __syncthreads();
  if (tid < 64) {
    const float si = s_imp[tid] + s_imp[64 + tid] + s_imp[128 + tid] + s_imp[192 + tid];
    const float sl = s_hard[tid] + s_hard[64 + tid] + s_hard[128 + tid] + s_hard[192 + tid];
    atomicAdd(imp_acc + tid, si);
    atomicAdd(load_acc + tid, sl);
  }
}

// ---------------- importance/load scale ----------------
__global__ void scale_kernel(const float* __restrict__ acc,
                             float* __restrict__ out_imp,
                             float* __restrict__ out_load) {
  const int tid = threadIdx.x;
  const float inv = 1.0f / 16384.0f;
  if (tid < 64)       out_imp[tid]        = acc[tid] * inv;
  else if (tid < 128) out_load[tid - 64]  = acc[tid] * inv;
}

extern "C" void kernel_launch(void* const* d_in, const int* in_sizes, int n_in,
                              void* d_out, int out_size, void* d_ws, size_t ws_size,
                              hipStream_t stream) {
  (void)in_sizes; (void)n_in; (void)out_size; (void)ws_size;
  const float* X     = (const float*)d_in[0];
  const float* Wg    = (const float*)d_in[1];
  const float* gamma = (const float*)d_in[2];
  const float* beta  = (const float*)d_in[3];
  const float* W1    = (const float*)d_in[4];
  const float* W2    = (const float*)d_in[5];
  float* out = (float*)d_out;

  char* ws = (char*)d_ws;
  _Float16* H      = (_Float16*)(ws);                    // 64 MB
  _Float16* W1h    = (_Float16*)(ws + 67108864ull);      // 4 MB
  float*    logits = (float*)  (ws + 71303168ull);       // 4 MB
  float*    diffz  = (float*)  (ws + 75497472ull);       // 64 KB
  float*    accs   = (float*)  (ws + 75563008ull);       // 512 B (imp[64], load[64])

  // out layout (all float32): idx[32768] | scores[32768] | probs[1048576] | imp[64] | load[64]
  float* out_idx    = out;
  float* out_scores = out + 32768;
  float* out_probs  = out + 65536;
  float* out_imp    = out + 1114112;
  float* out_load   = out + 1114176;

  hipMemsetAsync(diffz, 0, 65536 + 512, stream);
  ln_kernel<<<BS_TOK, 256, 0, stream>>>(X, gamma, beta, H);
  w1cast_kernel<<<(DHID * DIM) / (256 * 8), 256, 0, stream>>>(W1, W1h);
  gate_kernel<<<BS_TOK / 64, 256, 0, stream>>>(X, Wg, logits);
  g2_kernel<<<dim3(DHID / 128, BS_TOK / 128), 256, 0, stream>>>(H, W1h, W2, diffz);
  finalize_kernel<<<BS_TOK / 4, 256, 0, stream>>>(logits, diffz, out_idx, out_scores,
                                                  out_probs, accs, accs + 64);
  scale_kernel<<<1, 128, 0, stream>>>(accs, out_imp, out_load);
}